// Round 1
// 1265.925 us; speedup vs baseline: 1.2769x; 1.2769x over previous
//
#include <hip/hip_runtime.h>
#include <stdint.h>

typedef unsigned short u16;

#define IN_F   4096
#define OUT_F  11008
#define M_TOT  8192   /* 4*2048 */

__device__ __constant__ float NF4_TAB[16] = {
    -1.0f, -0.6961928009986877f, -0.5250730514526367f, -0.39491748809814453f,
    -0.28444138169288635f, -0.18477343022823334f, -0.09105003625154495f, 0.0f,
    0.07958029955625534f, 0.16093020141124725f, 0.24611230194568634f,
    0.33791524171829224f, 0.44070982933044434f, 0.5626170039176941f,
    0.7229568362236023f, 1.0f};

static __device__ __forceinline__ unsigned f2bf(float f) {
  unsigned u = __float_as_uint(f);
  u += 0x7fffu + ((u >> 16) & 1u);   // round-to-nearest-even
  return u >> 16;
}

// ---------------- dequant W: codes(int32)+absmax -> bf16, 8 elems/thread ----
__global__ __launch_bounds__(256) void dequant_w_kernel(
    const int* __restrict__ codes, const float* __restrict__ absmax,
    uint4* __restrict__ wout, int n8) {
  __shared__ float lut[16];
  if (threadIdx.x < 16) lut[threadIdx.x] = NF4_TAB[threadIdx.x];
  __syncthreads();
  int t = blockIdx.x * 256 + threadIdx.x;
  if (t >= n8) return;
  const int4* cp = (const int4*)codes + (size_t)t * 2;
  int4 c0 = cp[0];
  int4 c1 = cp[1];
  float am = absmax[t >> 3];          // 8 elems all inside one 64-block
  unsigned h0 = f2bf(lut[c0.x] * am) | (f2bf(lut[c0.y] * am) << 16);
  unsigned h1 = f2bf(lut[c0.z] * am) | (f2bf(lut[c0.w] * am) << 16);
  unsigned h2 = f2bf(lut[c1.x] * am) | (f2bf(lut[c1.y] * am) << 16);
  unsigned h3 = f2bf(lut[c1.z] * am) | (f2bf(lut[c1.w] * am) << 16);
  wout[t] = make_uint4(h0, h1, h2, h3);
}

// ---------------- convert x: fp32 -> bf16, 8 elems/thread -------------------
__global__ __launch_bounds__(256) void convert_x_kernel(
    const float4* __restrict__ x, uint4* __restrict__ xout, int n8) {
  int t = blockIdx.x * 256 + threadIdx.x;
  if (t >= n8) return;
  float4 a = x[(size_t)t * 2];
  float4 b = x[(size_t)t * 2 + 1];
  unsigned h0 = f2bf(a.x) | (f2bf(a.y) << 16);
  unsigned h1 = f2bf(a.z) | (f2bf(a.w) << 16);
  unsigned h2 = f2bf(b.x) | (f2bf(b.y) << 16);
  unsigned h3 = f2bf(b.z) | (f2bf(b.w) << 16);
  xout[t] = make_uint4(h0, h1, h2, h3);
}

// ---------------- 256x256 phase-split bf16 MFMA GEMM ------------------------
// C[M,N] = A[M,K] * B[N,K]^T.  8 waves (2M x 4N), BK=64, dbuf LDS 128 KiB,
// counted vmcnt (never 0 in loop), XOR-swizzled LDS (T2), setprio (T5),
// bijective XCD swizzle (T1).
typedef __attribute__((ext_vector_type(8))) short short8;
typedef __attribute__((ext_vector_type(4))) float f32x4;

static __device__ __forceinline__ void async_copy16(const u16* g, u16* l) {
  __builtin_amdgcn_global_load_lds(
      (const __attribute__((address_space(1))) unsigned int*)g,
      (__attribute__((address_space(3))) unsigned int*)l, 16, 0, 0);
}

__global__ __launch_bounds__(512, 2) void gemm256_bt_bf16_kernel(
    const u16* __restrict__ A,   // [M_TOT, IN_F] bf16 bits
    const u16* __restrict__ B,   // [OUT_F, IN_F] bf16 bits
    float* __restrict__ C) {     // [M_TOT, OUT_F]
  constexpr int K  = IN_F;
  constexpr int N  = OUT_F;
  constexpr int NT = K / 64;                 // 64 K-tiles
  __shared__ u16 lds[2][2][256 * 64];        // [dbuf][A|B][256 rows x 64 cols] = 128 KiB

  const int tid   = threadIdx.x;
  const int wave  = tid >> 6;                // 0..7
  const int lane  = tid & 63;
  const int wr    = wave >> 2;               // 0..1  (M dir, 128 rows each)
  const int wc    = wave & 3;                // 0..3  (N dir, 64 cols each)
  const int row16 = lane & 15;
  const int quad  = lane >> 4;
  const int swz   = (row16 & 7) << 3;        // elem-XOR for fragment reads

  // T1: bijective XCD swizzle. nwg = 1376 = 8 * 172 (divisible -> simple form).
  const int orig = blockIdx.x;
  const int tile = (orig & 7) * 172 + (orig >> 3);
  const int mb = tile / 43, nb = tile % 43;
  const int m0 = mb * 256, n0 = nb * 256;

  // staging geometry: wave w owns rows [w*32, w*32+32), 4 rounds of 8 rows.
  // global source column is pre-swizzled so linear global_load_lds dest +
  // XOR on ds_read form the same involution (rule #21).
  const int sr   = lane >> 3;                       // 0..7 row-in-round
  const int scol = ((lane & 7) ^ sr) << 3;          // pre-swizzled col (elems)
  const u16* ag = A + (size_t)(m0 + wave * 32 + sr) * K + scol;
  const u16* bg = B + (size_t)(n0 + wave * 32 + sr) * K + scol;
  const int ldsbase = wave * 32 * 64;               // elems

  f32x4 acc[8][4] = {};

  // prologue: stage K-tile 0 into buf 0 (8 loads/thread)
#pragma unroll
  for (int j = 0; j < 4; ++j)
    async_copy16(ag + (size_t)(j * 8) * K, &lds[0][0][ldsbase + j * 512]);
#pragma unroll
  for (int j = 0; j < 4; ++j)
    async_copy16(bg + (size_t)(j * 8) * K, &lds[0][1][ldsbase + j * 512]);

  int cur = 0;
  for (int t = 0; t < NT; ++t) {
    // stage next K-tile into the other buffer (clamped redundant reload at tail)
    const int tn = (t < NT - 1) ? t + 1 : t;
    {
      u16* An = &lds[cur ^ 1][0][0];
      u16* Bn = &lds[cur ^ 1][1][0];
#pragma unroll
      for (int j = 0; j < 4; ++j)
        async_copy16(ag + (size_t)(j * 8) * K + tn * 64, &An[ldsbase + j * 512]);
#pragma unroll
      for (int j = 0; j < 4; ++j)
        async_copy16(bg + (size_t)(j * 8) * K + tn * 64, &Bn[ldsbase + j * 512]);
    }
    // T4: counted wait — oldest 8 (this tile's loads) landed, 8 stay in flight.
    asm volatile("s_waitcnt vmcnt(8)\ns_barrier" ::: "memory");

    const u16* Ac = &lds[cur][0][0];
    const u16* Bc = &lds[cur][1][0];

    // B fragments for the whole K-tile (reused by all 4 phases): 8 x ds_read_b128
    short8 bf[4][2];
#pragma unroll
    for (int j = 0; j < 4; ++j)
#pragma unroll
      for (int kx = 0; kx < 2; ++kx)
        bf[j][kx] = *(const short8*)&Bc[(wc * 64 + j * 16 + row16) * 64 +
                                        ((kx * 32 + quad * 8) ^ swz)];

    // T3: 4 phases, each = {4 ds_read_b128 A-frags; 16 MFMA} between raw barriers
#pragma unroll
    for (int p = 0; p < 4; ++p) {
      if (p) asm volatile("s_barrier" ::: "memory");
      short8 af[2][2];
#pragma unroll
      for (int ii = 0; ii < 2; ++ii)
#pragma unroll
        for (int kx = 0; kx < 2; ++kx)
          af[ii][kx] = *(const short8*)&Ac[(wr * 128 + (p * 2 + ii) * 16 + row16) * 64 +
                                           ((kx * 32 + quad * 8) ^ swz)];
      __builtin_amdgcn_s_setprio(1);          // T5
#pragma unroll
      for (int ii = 0; ii < 2; ++ii)
#pragma unroll
        for (int j = 0; j < 4; ++j)
#pragma unroll
          for (int kx = 0; kx < 2; ++kx)
            acc[p * 2 + ii][j] = __builtin_amdgcn_mfma_f32_16x16x32_bf16(
                af[ii][kx], bf[j][kx], acc[p * 2 + ii][j], 0, 0, 0);
      __builtin_amdgcn_s_setprio(0);
    }
    // all waves done reading buf[cur] before anyone stages over it next iter
    asm volatile("s_barrier" ::: "memory");
    cur ^= 1;
  }
  asm volatile("s_waitcnt vmcnt(0)" ::: "memory");  // drain tail stage before exit

  // Epilogue: C/D layout col = lane&15, row = quad*4 + reg  [m89/m91]
#pragma unroll
  for (int i = 0; i < 8; ++i)
#pragma unroll
    for (int j = 0; j < 4; ++j)
#pragma unroll
      for (int r = 0; r < 4; ++r)
        C[(size_t)(m0 + wr * 128 + i * 16 + quad * 4 + r) * N +
          (n0 + wc * 64 + j * 16 + row16)] = acc[i][j][r];
}

// ---------------- fallback (ws too small): slow but correct -----------------
__global__ void fallback_kernel(const float* __restrict__ x,
                                const int* __restrict__ codes,
                                const float* __restrict__ absmax,
                                float* __restrict__ out) {
  __shared__ float lut[16];
  __shared__ float xs[16][17];
  __shared__ float ws[16][17];
  const int tx = threadIdx.x, ty = threadIdx.y;
  if (ty == 0 && tx < 16) lut[tx] = NF4_TAB[tx];
  __syncthreads();
  const int m  = blockIdx.y * 16 + ty;
  const int n0 = blockIdx.x * 16;
  float acc = 0.f;
  for (int k0 = 0; k0 < IN_F; k0 += 16) {
    xs[ty][tx] = x[(size_t)m * IN_F + k0 + tx];
    int idx = (n0 + ty) * IN_F + k0 + tx;
    ws[ty][tx] = lut[codes[idx]] * absmax[idx >> 6];
    __syncthreads();
#pragma unroll
    for (int kk = 0; kk < 16; ++kk) acc += xs[ty][kk] * ws[tx][kk];
    __syncthreads();
  }
  out[(size_t)m * OUT_F + n0 + tx] = acc;
}

// ---------------------------------------------------------------------------
extern "C" void kernel_launch(void* const* d_in, const int* in_sizes, int n_in,
                              void* d_out, int out_size, void* d_ws, size_t ws_size,
                              hipStream_t stream) {
  const float* x      = (const float*)d_in[0];  // [4,2048,4096] fp32
  const int*   codes  = (const int*)d_in[1];    // [11008,4096] int32 in [0,16)
  const float* absmax = (const float*)d_in[2];  // [704512] fp32
  float* out = (float*)d_out;                   // [4,2048,11008] fp32

  const size_t wBytes = (size_t)OUT_F * IN_F * 2;  // 90,177,536
  const size_t xBytes = (size_t)M_TOT * IN_F * 2;  // 67,108,864

  if (ws_size >= wBytes + xBytes) {
    u16* wq = (u16*)d_ws;
    u16* xq = (u16*)((char*)d_ws + wBytes);

    const int n8w = OUT_F * IN_F / 8;
    dequant_w_kernel<<<(n8w + 255) / 256, 256, 0, stream>>>(
        codes, absmax, (uint4*)wq, n8w);

    const int n8x = M_TOT * IN_F / 8;
    convert_x_kernel<<<(n8x + 255) / 256, 256, 0, stream>>>(
        (const float4*)x, (uint4*)xq, n8x);

    const int nwg = (M_TOT / 256) * (OUT_F / 256);  // 32 * 43 = 1376
    gemm256_bt_bf16_kernel<<<nwg, 512, 0, stream>>>(xq, wq, out);
  } else {
    dim3 blk(16, 16);
    dim3 grid(OUT_F / 16, M_TOT / 16);    // (688, 512)
    fallback_kernel<<<grid, blk, 0, stream>>>(x, codes, absmax, out);
  }
}

// Round 2
// 1172.770 us; speedup vs baseline: 1.3783x; 1.0794x over previous
//
#include <hip/hip_runtime.h>
#include <stdint.h>

typedef unsigned short u16;

#define IN_F   4096
#define OUT_F  11008
#define M_TOT  8192   /* 4*2048 */

__device__ __constant__ float NF4_TAB[16] = {
    -1.0f, -0.6961928009986877f, -0.5250730514526367f, -0.39491748809814453f,
    -0.28444138169288635f, -0.18477343022823334f, -0.09105003625154495f, 0.0f,
    0.07958029955625534f, 0.16093020141124725f, 0.24611230194568634f,
    0.33791524171829224f, 0.44070982933044434f, 0.5626170039176941f,
    0.7229568362236023f, 1.0f};

static __device__ __forceinline__ unsigned f2bf(float f) {
  unsigned u = __float_as_uint(f);
  u += 0x7fffu + ((u >> 16) & 1u);   // round-to-nearest-even
  return u >> 16;
}

// ---------------- dequant W: codes(int32)+absmax -> bf16, 8 elems/thread ----
__global__ __launch_bounds__(256) void dequant_w_kernel(
    const int* __restrict__ codes, const float* __restrict__ absmax,
    uint4* __restrict__ wout, int n8) {
  __shared__ float lut[16];
  if (threadIdx.x < 16) lut[threadIdx.x] = NF4_TAB[threadIdx.x];
  __syncthreads();
  int t = blockIdx.x * 256 + threadIdx.x;
  if (t >= n8) return;
  const int4* cp = (const int4*)codes + (size_t)t * 2;
  int4 c0 = cp[0];
  int4 c1 = cp[1];
  float am = absmax[t >> 3];          // 8 elems all inside one 64-block
  unsigned h0 = f2bf(lut[c0.x] * am) | (f2bf(lut[c0.y] * am) << 16);
  unsigned h1 = f2bf(lut[c0.z] * am) | (f2bf(lut[c0.w] * am) << 16);
  unsigned h2 = f2bf(lut[c1.x] * am) | (f2bf(lut[c1.y] * am) << 16);
  unsigned h3 = f2bf(lut[c1.z] * am) | (f2bf(lut[c1.w] * am) << 16);
  wout[t] = make_uint4(h0, h1, h2, h3);
}

// ---------------- convert x: fp32 -> bf16, 8 elems/thread -------------------
__global__ __launch_bounds__(256) void convert_x_kernel(
    const float4* __restrict__ x, uint4* __restrict__ xout, int n8) {
  int t = blockIdx.x * 256 + threadIdx.x;
  if (t >= n8) return;
  float4 a = x[(size_t)t * 2];
  float4 b = x[(size_t)t * 2 + 1];
  unsigned h0 = f2bf(a.x) | (f2bf(a.y) << 16);
  unsigned h1 = f2bf(a.z) | (f2bf(a.w) << 16);
  unsigned h2 = f2bf(b.x) | (f2bf(b.y) << 16);
  unsigned h3 = f2bf(b.z) | (f2bf(b.w) << 16);
  xout[t] = make_uint4(h0, h1, h2, h3);
}

// ---------------- 256x256 8-phase bf16 MFMA GEMM (m201 template) ------------
// C[M,N] = A[M,K] * B[N,K]^T.  8 waves (2M x 4N), BK=64, 2 K-tiles/iter,
// 8 phases each {ds_read ; 1-2 half-tile stages ; barrier ; MFMA ; barrier},
// vmcnt(4) only at phases 4/8 (T3+T4), XOR-swizzle (T2), setprio (T5),
// bijective XCD swizzle (T1).
typedef __attribute__((ext_vector_type(8))) short short8;
typedef __attribute__((ext_vector_type(4))) float f32x4;

static __device__ __forceinline__ void async_copy16(const u16* g, u16* l) {
  __builtin_amdgcn_global_load_lds(
      (const __attribute__((address_space(1))) unsigned int*)g,
      (__attribute__((address_space(3))) unsigned int*)l, 16, 0, 0);
}

// Stage one 128-row half of A or B for K-tile KT into buf BUF (2 loads/thread).
// LDS dest is wave-uniform (HW adds lane*16B); global col is pre-swizzled so
// the store/read permutations form the same involution (rule #21).
#define STAGE(BUF, AB, HALF, GP, KT)                                         \
  do {                                                                       \
    const u16* g_ = (GP) + (size_t)((HALF) * 128) * K + (KT) * 64;           \
    u16* l_ = &lds[BUF][AB][((HALF) * 128 + wave * 8) * 64];                 \
    async_copy16(g_, l_);                                                    \
    async_copy16(g_ + (size_t)64 * K, l_ + 64 * 64);                         \
  } while (0)

// One phase: quadrant P of the tile in buf BUF. LOADB only on the tile's
// first phase (B-frags live in regs for all 4 quadrants). P is a literal
// (static acc indexing, rule #20).
#define PHASE(BUF, P, LOADB, ...)                                            \
  do {                                                                       \
    if (LOADB) {                                                             \
      const u16* Bc_ = &lds[BUF][1][0];                                      \
      _Pragma("unroll") for (int j = 0; j < 4; ++j)                          \
          _Pragma("unroll") for (int kx = 0; kx < 2; ++kx)                   \
              bf[j][kx] = *(const short8*)&Bc_[(wc * 64 + j * 16 + row16) *  \
                                                   64 +                      \
                                               ((kx * 32 + quad * 8) ^ swz)];\
    }                                                                        \
    short8 af_[2][2];                                                        \
    {                                                                        \
      const u16* Ac_ = &lds[BUF][0][0];                                      \
      _Pragma("unroll") for (int ii = 0; ii < 2; ++ii)                       \
          _Pragma("unroll") for (int kx = 0; kx < 2; ++kx)                   \
              af_[ii][kx] = *(const short8*)&Ac_[(wr * 128 +                 \
                                                  ((P)*2 + ii) * 16 +        \
                                                  row16) * 64 +              \
                                                 ((kx * 32 + quad * 8) ^     \
                                                  swz)];                     \
    }                                                                        \
    __VA_ARGS__;                                                             \
    asm volatile("s_barrier" ::: "memory");                                  \
    __builtin_amdgcn_s_setprio(1);                                           \
    _Pragma("unroll") for (int ii = 0; ii < 2; ++ii)                         \
        _Pragma("unroll") for (int j = 0; j < 4; ++j)                        \
            _Pragma("unroll") for (int kx = 0; kx < 2; ++kx)                 \
                acc[(P)*2 + ii][j] = __builtin_amdgcn_mfma_f32_16x16x32_bf16(\
                    af_[ii][kx], bf[j][kx], acc[(P)*2 + ii][j], 0, 0, 0);    \
    __builtin_amdgcn_s_setprio(0);                                           \
  } while (0)

__global__ __launch_bounds__(512, 2) void gemm256_bt_bf16_kernel(
    const u16* __restrict__ A,   // [M_TOT, IN_F] bf16 bits
    const u16* __restrict__ B,   // [OUT_F, IN_F] bf16 bits
    float* __restrict__ C) {     // [M_TOT, OUT_F]
  constexpr int K   = IN_F;
  constexpr int N   = OUT_F;
  constexpr int NT  = K / 64;                // 64 K-tiles
  constexpr int NIT = NT / 2;                // 32 iterations (2 tiles each)
  __shared__ u16 lds[2][2][256 * 64];        // [buf][A|B][256 x 64] = 128 KiB

  const int tid   = threadIdx.x;
  const int wave  = tid >> 6;                // 0..7
  const int lane  = tid & 63;
  const int wr    = wave >> 2;               // 0..1  (M dir, 128 rows)
  const int wc    = wave & 3;                // 0..3  (N dir, 64 cols)
  const int row16 = lane & 15;
  const int quad  = lane >> 4;
  const int swz   = (row16 & 7) << 3;        // elem-XOR for fragment reads

  // T1: bijective XCD swizzle. nwg = 1376 = 8 * 172.
  const int orig = blockIdx.x;
  const int tile = (orig & 7) * 172 + (orig >> 3);
  const int mb = tile / 43, nb = tile % 43;
  const int m0 = mb * 256, n0 = nb * 256;

  // staging base: lane l covers row wave*8 + (l>>3), col-slot (l&7) (16B),
  // pre-swizzled global column ((l&7)^(l>>3))*8
  const int sr = lane >> 3;
  const int sc = ((lane & 7) ^ sr) << 3;
  const u16* agp = A + (size_t)(m0 + wave * 8 + sr) * K + sc;
  const u16* bgp = B + (size_t)(n0 + wave * 8 + sr) * K + sc;

  f32x4 acc[8][4] = {};
  short8 bf[4][2];

  // Prologue: tile0 (A+B) -> buf0, tile1 B -> buf1  (12 loads/thread).
  // Need first 8 landed, 4 younger allowed in flight -> vmcnt(4).
  STAGE(0, 0, 0, agp, 0);
  STAGE(0, 0, 1, agp, 0);
  STAGE(0, 1, 0, bgp, 0);
  STAGE(0, 1, 1, bgp, 0);
  STAGE(1, 1, 0, bgp, 1);
  STAGE(1, 1, 1, bgp, 1);
  asm volatile("s_waitcnt vmcnt(4)\n\ts_barrier" ::: "memory");

  for (int j = 0; j < NIT; ++j) {
    const int kt1 = 2 * j + 1;                               // odd tile (real)
    const int kt2 = (2 * j + 2 < NT) ? 2 * j + 2 : NT - 1;   // clamped tail
    const int kt3 = (2 * j + 3 < NT) ? 2 * j + 3 : NT - 1;
    // ---- tile 2j from buf0 ----
    PHASE(0, 0, true,  STAGE(1, 0, 0, agp, kt1));            // A0(2j+1)
    asm volatile("s_barrier" ::: "memory");
    PHASE(0, 1, false, STAGE(1, 0, 1, agp, kt1);             // A1(2j+1)
                       STAGE(0, 1, 0, bgp, kt2));            // B0(2j+2)
    asm volatile("s_barrier" ::: "memory");
    PHASE(0, 2, false, STAGE(0, 1, 1, bgp, kt2));            // B1(2j+2)
    asm volatile("s_barrier" ::: "memory");
    PHASE(0, 3, false, ((void)0));
    // need tile 2j+1 complete; younger in flight: B0,B1(2j+2) = 4 loads
    asm volatile("s_waitcnt vmcnt(4)\n\ts_barrier" ::: "memory");
    // ---- tile 2j+1 from buf1 ----
    PHASE(1, 0, true,  STAGE(0, 0, 0, agp, kt2));            // A0(2j+2)
    asm volatile("s_barrier" ::: "memory");
    PHASE(1, 1, false, STAGE(0, 0, 1, agp, kt2);             // A1(2j+2)
                       STAGE(1, 1, 0, bgp, kt3));            // B0(2j+3)
    asm volatile("s_barrier" ::: "memory");
    PHASE(1, 2, false, STAGE(1, 1, 1, bgp, kt3));            // B1(2j+3)
    asm volatile("s_barrier" ::: "memory");
    PHASE(1, 3, false, ((void)0));
    // need tile 2j+2 complete; younger in flight: B0,B1(2j+3) = 4 loads
    asm volatile("s_waitcnt vmcnt(4)\n\ts_barrier" ::: "memory");
  }
  asm volatile("s_waitcnt vmcnt(0)" ::: "memory");  // drain dummy tail stages

  // Epilogue: C/D layout col = lane&15, row = quad*4 + reg  [m89/m91]
#pragma unroll
  for (int i = 0; i < 8; ++i)
#pragma unroll
    for (int j = 0; j < 4; ++j)
#pragma unroll
      for (int r = 0; r < 4; ++r)
        C[(size_t)(m0 + wr * 128 + i * 16 + quad * 4 + r) * N +
          (n0 + wc * 64 + j * 16 + row16)] = acc[i][j][r];
}

// ---------------- fallback (ws too small): slow but correct -----------------
__global__ void fallback_kernel(const float* __restrict__ x,
                                const int* __restrict__ codes,
                                const float* __restrict__ absmax,
                                float* __restrict__ out) {
  __shared__ float lut[16];
  __shared__ float xs[16][17];
  __shared__ float ws[16][17];
  const int tx = threadIdx.x, ty = threadIdx.y;
  if (ty == 0 && tx < 16) lut[tx] = NF4_TAB[tx];
  __syncthreads();
  const int m  = blockIdx.y * 16 + ty;
  const int n0 = blockIdx.x * 16;
  float acc = 0.f;
  for (int k0 = 0; k0 < IN_F; k0 += 16) {
    xs[ty][tx] = x[(size_t)m * IN_F + k0 + tx];
    int idx = (n0 + ty) * IN_F + k0 + tx;
    ws[ty][tx] = lut[codes[idx]] * absmax[idx >> 6];
    __syncthreads();
#pragma unroll
    for (int kk = 0; kk < 16; ++kk) acc += xs[ty][kk] * ws[tx][kk];
    __syncthreads();
  }
  out[(size_t)m * OUT_F + n0 + tx] = acc;
}

// ---------------------------------------------------------------------------
extern "C" void kernel_launch(void* const* d_in, const int* in_sizes, int n_in,
                              void* d_out, int out_size, void* d_ws, size_t ws_size,
                              hipStream_t stream) {
  const float* x      = (const float*)d_in[0];  // [4,2048,4096] fp32
  const int*   codes  = (const int*)d_in[1];    // [11008,4096] int32 in [0,16)
  const float* absmax = (const float*)d_in[2];  // [704512] fp32
  float* out = (float*)d_out;                   // [4,2048,11008] fp32

  const size_t wBytes = (size_t)OUT_F * IN_F * 2;  // 90,177,536
  const size_t xBytes = (size_t)M_TOT * IN_F * 2;  // 67,108,864

  if (ws_size >= wBytes + xBytes) {
    u16* wq = (u16*)d_ws;
    u16* xq = (u16*)((char*)d_ws + wBytes);

    const int n8w = OUT_F * IN_F / 8;
    dequant_w_kernel<<<(n8w + 255) / 256, 256, 0, stream>>>(
        codes, absmax, (uint4*)wq, n8w);

    const int n8x = M_TOT * IN_F / 8;
    convert_x_kernel<<<(n8x + 255) / 256, 256, 0, stream>>>(
        (const float4*)x, (uint4*)xq, n8x);

    const int nwg = (M_TOT / 256) * (OUT_F / 256);  // 32 * 43 = 1376
    gemm256_bt_bf16_kernel<<<nwg, 512, 0, stream>>>(xq, wq, out);
  } else {
    dim3 blk(16, 16);
    dim3 grid(OUT_F / 16, M_TOT / 16);    // (688, 512)
    fallback_kernel<<<grid, blk, 0, stream>>>(x, codes, absmax, out);
  }
}